// Round 1
// baseline (420.118 us; speedup 1.0000x reference)
//
#include <hip/hip_runtime.h>
#include <hip/hip_bf16.h>
#include <stdint.h>

// ---------------------------------------------------------------------------
// RowParallelLinearSparse: out[M,N] = x[M,K] · (W ⊙ nm_mask(W))[N,K]^T + bias
// M=16384 (S*B), N=O=2048, K=H=2048.  Strategy: bf16 MFMA (threshold is a
// bf16-floor threshold), m97-verified 128x128/BK=64 global_load_lds GEMM.
// ---------------------------------------------------------------------------

typedef short  bf16x8  __attribute__((ext_vector_type(8)));
typedef float  floatx4 __attribute__((ext_vector_type(4)));

#define AS1 __attribute__((address_space(1)))
#define AS3 __attribute__((address_space(3)))

__device__ __forceinline__ void async_copy16(const void* g, void* l) {
    __builtin_amdgcn_global_load_lds((const AS1 unsigned int*)g,
                                     (AS3 unsigned int*)l, 16, 0, 0);
}

__device__ __forceinline__ unsigned short f2bf(float f) {
    union { float f; unsigned int u; } v;
    v.f = f;
    // round-to-nearest-even
    unsigned int r = (v.u + 0x7fffu + ((v.u >> 16) & 1u)) >> 16;
    return (unsigned short)r;
}

// --- x: fp32 -> bf16, 8 elements/thread --------------------------------------
__global__ void cvt_bf16_x8(const float4* __restrict__ in,
                            uint4* __restrict__ out, long n8) {
    long i = (long)blockIdx.x * blockDim.x + threadIdx.x;
    if (i >= n8) return;
    float4 f0 = in[2 * i];
    float4 f1 = in[2 * i + 1];
    uint4 o;
    o.x = (unsigned)f2bf(f0.x) | ((unsigned)f2bf(f0.y) << 16);
    o.y = (unsigned)f2bf(f0.z) | ((unsigned)f2bf(f0.w) << 16);
    o.z = (unsigned)f2bf(f1.x) | ((unsigned)f2bf(f1.y) << 16);
    o.w = (unsigned)f2bf(f1.z) | ((unsigned)f2bf(f1.w) << 16);
    out[i] = o;
}

// --- W: apply 2:4 mask (zero 2 smallest |w| per group of 4, stable-argsort
//        tie order) and convert to bf16. One thread per group. ---------------
__global__ void sparsify_w(const float4* __restrict__ W,
                           unsigned long long* __restrict__ Wb, int ngroups) {
    int g = blockIdx.x * blockDim.x + threadIdx.x;
    if (g >= ngroups) return;
    float4 w4 = W[g];
    float v[4] = {w4.x, w4.y, w4.z, w4.w};
    float a[4] = {fabsf(w4.x), fabsf(w4.y), fabsf(w4.z), fabsf(w4.w)};
    unsigned long long packed = 0;
#pragma unroll
    for (int i = 0; i < 4; i++) {
        int rank = 0;
#pragma unroll
        for (int j = 0; j < 4; j++)
            rank += (a[j] < a[i]) || (a[j] == a[i] && j < i);
        // stable ascending rank; zero the 2 smallest (rank 0,1), keep 2,3
        unsigned short b = (rank >= 2) ? f2bf(v[i]) : (unsigned short)0;
        packed |= ((unsigned long long)b) << (16 * i);
    }
    Wb[g] = packed;
}

// --- bf16 B^T GEMM, m97 structure: 128x128 tile, BK=64, 4 waves (2x2),
//     4x4 mfma_f32_16x16x32_bf16 per wave, global_load_lds width=16. --------
__global__ __launch_bounds__(256) void gemm_bt_bf16(
    const unsigned short* __restrict__ A,   // [M,K] bf16
    const unsigned short* __restrict__ B,   // [N,K] bf16 (sparse W)
    const float* __restrict__ bias,         // [N]
    float* __restrict__ C,                  // [M,N] fp32
    int M, int N, int K) {
    __shared__ unsigned short lA[128 * 64];   // 16 KB, unpadded (global_load_lds)
    __shared__ unsigned short lB[128 * 64];   // 16 KB

    const int tid  = threadIdx.x;
    const int wid  = tid >> 6;
    const int lane = tid & 63;

    const int bm = blockIdx.y * 128;
    const int bn = blockIdx.x * 128;

    const int wm = (wid & 1) * 64;    // wave's 64-row slab of C tile
    const int wn = (wid >> 1) * 64;   // wave's 64-col slab

    // staging: each wave stages 32 rows of each tile; per instr a wave writes
    // 1024 contiguous LDS bytes = 8 rows of 128 B.
    const int s_row = lane >> 3;          // 0..7
    const int s_col = (lane & 7) * 8;     // bf16 col, 16B chunks

    const unsigned short* Ag = A + (size_t)(bm + wid * 32 + s_row) * K + s_col;
    const unsigned short* Bg = B + (size_t)(bn + wid * 32 + s_row) * K + s_col;
    unsigned short* lAw = &lA[(wid * 32) * 64];
    unsigned short* lBw = &lB[(wid * 32) * 64];

    floatx4 acc[4][4];
#pragma unroll
    for (int i = 0; i < 4; i++)
#pragma unroll
        for (int j = 0; j < 4; j++)
            acc[i][j] = (floatx4){0.f, 0.f, 0.f, 0.f};

    const int fm = lane & 15;            // A/B operand 16-dim index
    const int fq = (lane >> 4) * 8;      // k sub-offset

    for (int kt = 0; kt < K; kt += 64) {
#pragma unroll
        for (int i = 0; i < 4; i++) {
            async_copy16(Ag + (size_t)i * 8 * K + kt, lAw + i * 8 * 64);
            async_copy16(Bg + (size_t)i * 8 * K + kt, lBw + i * 8 * 64);
        }
        __syncthreads();   // compiler emits vmcnt(0) drain before s_barrier

#pragma unroll
        for (int ks = 0; ks < 2; ks++) {
            const int ko = ks * 32 + fq;
            bf16x8 af[4], bfv[4];
#pragma unroll
            for (int i = 0; i < 4; i++) {
                af[i]  = *(const bf16x8*)&lA[(wm + i * 16 + fm) * 64 + ko];
                bfv[i] = *(const bf16x8*)&lB[(wn + i * 16 + fm) * 64 + ko];
            }
#pragma unroll
            for (int i = 0; i < 4; i++)
#pragma unroll
                for (int j = 0; j < 4; j++)
                    acc[i][j] = __builtin_amdgcn_mfma_f32_16x16x32_bf16(
                        af[i], bfv[j], acc[i][j], 0, 0, 0);
        }
        __syncthreads();
    }

    // epilogue: C/D layout col=lane&15, row=(lane>>4)*4+reg  (m89-verified)
    const int cn = lane & 15;
    const int cm = (lane >> 4) * 4;
#pragma unroll
    for (int j = 0; j < 4; j++) {
        const int col = bn + wn + j * 16 + cn;
        const float bv = bias[col];
#pragma unroll
        for (int i = 0; i < 4; i++) {
            const size_t rbase = (size_t)(bm + wm + i * 16 + cm) * N + col;
#pragma unroll
            for (int r = 0; r < 4; r++)
                C[rbase + (size_t)r * N] = acc[i][j][r] + bv;
        }
    }
}

extern "C" void kernel_launch(void* const* d_in, const int* in_sizes, int n_in,
                              void* d_out, int out_size, void* d_ws, size_t ws_size,
                              hipStream_t stream) {
    const float* x    = (const float*)d_in[0];   // [S,B,H] fp32
    const float* w    = (const float*)d_in[1];   // [O,H]  fp32
    const float* bias = (const float*)d_in[2];   // [O]    fp32
    float* out = (float*)d_out;

    const int O = in_sizes[2];
    const int H = in_sizes[1] / O;
    const long M = (long)in_sizes[0] / H;        // S*B = 16384

    // workspace: x_bf16 [M*H] then w_bf16 [O*H]
    unsigned short* xb = (unsigned short*)d_ws;
    unsigned short* wb = xb + (size_t)M * H;

    const long n8 = (long)M * H / 8;
    cvt_bf16_x8<<<dim3((n8 + 255) / 256), dim3(256), 0, stream>>>(
        (const float4*)x, (uint4*)xb, n8);

    const int ng = O * H / 4;
    sparsify_w<<<dim3((ng + 255) / 256), dim3(256), 0, stream>>>(
        (const float4*)w, (unsigned long long*)wb, ng);

    dim3 grid(O / 128, (unsigned)(M / 128));     // (16, 128)
    gemm_bt_bf16<<<grid, dim3(256), 0, stream>>>(xb, wb, bias, out,
                                                 (int)M, O, H);
}

// Round 2
// 394.797 us; speedup vs baseline: 1.0641x; 1.0641x over previous
//
#include <hip/hip_runtime.h>
#include <hip/hip_bf16.h>
#include <stdint.h>

// ---------------------------------------------------------------------------
// RowParallelLinearSparse: out[M,N] = x[M,K] · (W ⊙ nm_mask(W))[N,K]^T + bias
// M=16384 (S*B), N=O=2048, K=H=2048.  bf16 MFMA, m97 128x128/BK=64 structure
// + XOR-swizzled LDS layout (swizzle applied on the GLOBAL source column so
// global_load_lds' wave-uniform LDS dest still works):
//   LDS[row][chunk c] = G[row][chunk c ^ (row&7)]   (chunk = 16B)
// ---------------------------------------------------------------------------

typedef short  bf16x8  __attribute__((ext_vector_type(8)));
typedef float  floatx4 __attribute__((ext_vector_type(4)));

#define AS1 __attribute__((address_space(1)))
#define AS3 __attribute__((address_space(3)))

__device__ __forceinline__ void async_copy16(const void* g, void* l) {
    __builtin_amdgcn_global_load_lds((const AS1 unsigned int*)g,
                                     (AS3 unsigned int*)l, 16, 0, 0);
}

__device__ __forceinline__ unsigned short f2bf(float f) {
    union { float f; unsigned int u; } v;
    v.f = f;
    unsigned int r = (v.u + 0x7fffu + ((v.u >> 16) & 1u)) >> 16;  // RNE
    return (unsigned short)r;
}

// --- x: fp32 -> bf16, 8 elements/thread --------------------------------------
__global__ void cvt_bf16_x8(const float4* __restrict__ in,
                            uint4* __restrict__ out, long n8) {
    long i = (long)blockIdx.x * blockDim.x + threadIdx.x;
    if (i >= n8) return;
    float4 f0 = in[2 * i];
    float4 f1 = in[2 * i + 1];
    uint4 o;
    o.x = (unsigned)f2bf(f0.x) | ((unsigned)f2bf(f0.y) << 16);
    o.y = (unsigned)f2bf(f0.z) | ((unsigned)f2bf(f0.w) << 16);
    o.z = (unsigned)f2bf(f1.x) | ((unsigned)f2bf(f1.y) << 16);
    o.w = (unsigned)f2bf(f1.z) | ((unsigned)f2bf(f1.w) << 16);
    out[i] = o;
}

// --- W: 2:4 mask (zero 2 smallest |w| per group of 4, stable-argsort tie
//        order) -> bf16. One thread per group. -------------------------------
__global__ void sparsify_w(const float4* __restrict__ W,
                           unsigned long long* __restrict__ Wb, int ngroups) {
    int g = blockIdx.x * blockDim.x + threadIdx.x;
    if (g >= ngroups) return;
    float4 w4 = W[g];
    float v[4] = {w4.x, w4.y, w4.z, w4.w};
    float a[4] = {fabsf(w4.x), fabsf(w4.y), fabsf(w4.z), fabsf(w4.w)};
    unsigned long long packed = 0;
#pragma unroll
    for (int i = 0; i < 4; i++) {
        int rank = 0;
#pragma unroll
        for (int j = 0; j < 4; j++)
            rank += (a[j] < a[i]) || (a[j] == a[i] && j < i);
        unsigned short b = (rank >= 2) ? f2bf(v[i]) : (unsigned short)0;
        packed |= ((unsigned long long)b) << (16 * i);
    }
    Wb[g] = packed;
}

// --- bf16 B^T GEMM: 128x128 tile, BK=64, 4 waves (2x2), 4x4 16x16x32 MFMA,
//     global_load_lds width=16, XOR-swizzled LDS. ---------------------------
__global__ __launch_bounds__(256) void gemm_bt_bf16(
    const unsigned short* __restrict__ A,   // [M,K] bf16
    const unsigned short* __restrict__ B,   // [N,K] bf16 (sparse W)
    const float* __restrict__ bias,         // [N]
    float* __restrict__ C,                  // [M,N] fp32
    int M, int N, int K) {
    __shared__ unsigned short lA[128 * 64];   // 16 KB, unpadded
    __shared__ unsigned short lB[128 * 64];   // 16 KB

    const int tid  = threadIdx.x;
    const int wid  = tid >> 6;
    const int lane = tid & 63;

    const int bm = blockIdx.y * 128;
    const int bn = blockIdx.x * 128;

    const int wm = (wid & 1) * 64;
    const int wn = (wid >> 1) * 64;

    // staging: wave stages 32 rows/tile; per instr 1024 contiguous LDS bytes.
    // lane L: row = L>>3, LDS chunk = L&7, GLOBAL chunk = (L&7) ^ (L>>3).
    const int s_row   = lane >> 3;                    // 0..7
    const int s_chunk = lane & 7;
    const int s_col   = (s_chunk ^ s_row) * 8;        // bf16 elems (swizzled src)

    const unsigned short* Ag = A + (size_t)(bm + wid * 32 + s_row) * K + s_col;
    const unsigned short* Bg = B + (size_t)(bn + wid * 32 + s_row) * K + s_col;
    unsigned short* lAw = &lA[(wid * 32) * 64];
    unsigned short* lBw = &lB[(wid * 32) * 64];

    floatx4 acc[4][4];
#pragma unroll
    for (int i = 0; i < 4; i++)
#pragma unroll
        for (int j = 0; j < 4; j++)
            acc[i][j] = (floatx4){0.f, 0.f, 0.f, 0.f};

    const int fm = lane & 15;        // operand row (16-dim)
    const int q  = lane >> 4;        // quarter-wave -> k chunk
    const int sw = fm & 7;           // row swizzle factor

    for (int kt = 0; kt < K; kt += 64) {
#pragma unroll
        for (int i = 0; i < 4; i++) {
            async_copy16(Ag + (size_t)i * 8 * K + kt, lAw + i * 8 * 64);
            async_copy16(Bg + (size_t)i * 8 * K + kt, lBw + i * 8 * 64);
        }
        __syncthreads();

#pragma unroll
        for (int ks = 0; ks < 2; ks++) {
            // logical chunk = ks*4 + q; swizzled LDS chunk = that ^ (row&7)
            const int ko = ((ks * 4 + q) ^ sw) * 8;   // bf16 elem offset in row
            bf16x8 af[4], bfv[4];
#pragma unroll
            for (int i = 0; i < 4; i++) {
                af[i]  = *(const bf16x8*)&lA[(wm + i * 16 + fm) * 64 + ko];
                bfv[i] = *(const bf16x8*)&lB[(wn + i * 16 + fm) * 64 + ko];
            }
#pragma unroll
            for (int i = 0; i < 4; i++)
#pragma unroll
                for (int j = 0; j < 4; j++)
                    acc[i][j] = __builtin_amdgcn_mfma_f32_16x16x32_bf16(
                        af[i], bfv[j], acc[i][j], 0, 0, 0);
        }
        __syncthreads();
    }

    // epilogue: C/D layout col=lane&15, row=(lane>>4)*4+reg  (m89-verified)
    const int cn = lane & 15;
    const int cm = (lane >> 4) * 4;
#pragma unroll
    for (int j = 0; j < 4; j++) {
        const int col = bn + wn + j * 16 + cn;
        const float bv = bias[col];
#pragma unroll
        for (int i = 0; i < 4; i++) {
            const size_t rbase = (size_t)(bm + wm + i * 16 + cm) * N + col;
#pragma unroll
            for (int r = 0; r < 4; r++)
                C[rbase + (size_t)r * N] = acc[i][j][r] + bv;
        }
    }
}

extern "C" void kernel_launch(void* const* d_in, const int* in_sizes, int n_in,
                              void* d_out, int out_size, void* d_ws, size_t ws_size,
                              hipStream_t stream) {
    const float* x    = (const float*)d_in[0];   // [S,B,H] fp32
    const float* w    = (const float*)d_in[1];   // [O,H]  fp32
    const float* bias = (const float*)d_in[2];   // [O]    fp32
    float* out = (float*)d_out;

    const int O = in_sizes[2];
    const int H = in_sizes[1] / O;
    const long M = (long)in_sizes[0] / H;        // S*B = 16384

    unsigned short* xb = (unsigned short*)d_ws;            // [M*H] bf16
    unsigned short* wb = xb + (size_t)M * H;               // [O*H] bf16

    const long n8 = (long)M * H / 8;
    cvt_bf16_x8<<<dim3((n8 + 255) / 256), dim3(256), 0, stream>>>(
        (const float4*)x, (uint4*)xb, n8);

    const int ng = O * H / 4;
    sparsify_w<<<dim3((ng + 255) / 256), dim3(256), 0, stream>>>(
        (const float4*)w, (unsigned long long*)wb, ng);

    dim3 grid(O / 128, (unsigned)(M / 128));     // (16, 128)
    gemm_bt_bf16<<<grid, dim3(256), 0, stream>>>(xb, wb, bias, out,
                                                 (int)M, O, H);
}

// Round 3
// 393.513 us; speedup vs baseline: 1.0676x; 1.0033x over previous
//
#include <hip/hip_runtime.h>
#include <hip/hip_bf16.h>
#include <stdint.h>

// ---------------------------------------------------------------------------
// RowParallelLinearSparse: out[M,N] = x[M,K] · (W ⊙ nm_mask(W))[N,K]^T + bias
// M=16384 (S*B), N=O=2048, K=H=2048.  bf16 MFMA, m97 128x128/BK=64 structure,
// XOR-swizzled LDS (conflict-free, verified R2: SQ_LDS_BANK_CONFLICT=0),
// + XCD-ownership block swizzle: each XCD owns 2 N-columns (B slice stays
// L2-resident) and walks private M-bands so A staging hits its own L2.
// ---------------------------------------------------------------------------

typedef short  bf16x8  __attribute__((ext_vector_type(8)));
typedef float  floatx4 __attribute__((ext_vector_type(4)));

#define AS1 __attribute__((address_space(1)))
#define AS3 __attribute__((address_space(3)))

__device__ __forceinline__ void async_copy16(const void* g, void* l) {
    __builtin_amdgcn_global_load_lds((const AS1 unsigned int*)g,
                                     (AS3 unsigned int*)l, 16, 0, 0);
}

__device__ __forceinline__ unsigned short f2bf(float f) {
    union { float f; unsigned int u; } v;
    v.f = f;
    unsigned int r = (v.u + 0x7fffu + ((v.u >> 16) & 1u)) >> 16;  // RNE
    return (unsigned short)r;
}

// --- x: fp32 -> bf16, 8 elements/thread --------------------------------------
__global__ void cvt_bf16_x8(const float4* __restrict__ in,
                            uint4* __restrict__ out, long n8) {
    long i = (long)blockIdx.x * blockDim.x + threadIdx.x;
    if (i >= n8) return;
    float4 f0 = in[2 * i];
    float4 f1 = in[2 * i + 1];
    uint4 o;
    o.x = (unsigned)f2bf(f0.x) | ((unsigned)f2bf(f0.y) << 16);
    o.y = (unsigned)f2bf(f0.z) | ((unsigned)f2bf(f0.w) << 16);
    o.z = (unsigned)f2bf(f1.x) | ((unsigned)f2bf(f1.y) << 16);
    o.w = (unsigned)f2bf(f1.z) | ((unsigned)f2bf(f1.w) << 16);
    out[i] = o;
}

// --- W: 2:4 mask (zero 2 smallest |w| per group of 4, stable-argsort tie
//        order) -> bf16. One thread per group. -------------------------------
__global__ void sparsify_w(const float4* __restrict__ W,
                           unsigned long long* __restrict__ Wb, int ngroups) {
    int g = blockIdx.x * blockDim.x + threadIdx.x;
    if (g >= ngroups) return;
    float4 w4 = W[g];
    float v[4] = {w4.x, w4.y, w4.z, w4.w};
    float a[4] = {fabsf(w4.x), fabsf(w4.y), fabsf(w4.z), fabsf(w4.w)};
    unsigned long long packed = 0;
#pragma unroll
    for (int i = 0; i < 4; i++) {
        int rank = 0;
#pragma unroll
        for (int j = 0; j < 4; j++)
            rank += (a[j] < a[i]) || (a[j] == a[i] && j < i);
        unsigned short b = (rank >= 2) ? f2bf(v[i]) : (unsigned short)0;
        packed |= ((unsigned long long)b) << (16 * i);
    }
    Wb[g] = packed;
}

// --- bf16 B^T GEMM: 128x128 tile, BK=64, 4 waves (2x2), 4x4 16x16x32 MFMA,
//     global_load_lds width=16, XOR-swizzled LDS, XCD-ownership swizzle. ----
__global__ __launch_bounds__(256) void gemm_bt_bf16(
    const unsigned short* __restrict__ A,   // [M,K] bf16
    const unsigned short* __restrict__ B,   // [N,K] bf16 (sparse W)
    const float* __restrict__ bias,         // [N]
    float* __restrict__ C,                  // [M,N] fp32
    int M, int N, int K) {
    __shared__ unsigned short lA[128 * 64];   // 16 KB, unpadded
    __shared__ unsigned short lB[128 * 64];   // 16 KB

    const int tid  = threadIdx.x;
    const int wid  = tid >> 6;
    const int lane = tid & 63;

    // XCD-ownership swizzle (perf-only permutation):
    //   id -> xcd = id&7 (HW round-robin), s = id>>3
    //   bn-block = xcd*2 + (s&1)   (each XCD owns 2 of 16 N-columns)
    //   bm-block = s>>1            (private M-band run; x-pair adjacent)
    const int id  = blockIdx.x;
    const int nbx = N >> 7;                  // N-blocks (16)
    int bxi, byi;
    if (nbx == 16) {
        const int xcd = id & 7;
        const int s   = id >> 3;
        bxi = xcd * 2 + (s & 1);
        byi = s >> 1;
    } else {                                 // fallback: plain 2D decompose
        bxi = id % nbx;
        byi = id / nbx;
    }
    const int bm = byi * 128;
    const int bn = bxi * 128;

    const int wm = (wid & 1) * 64;
    const int wn = (wid >> 1) * 64;

    // staging: wave stages 32 rows/tile; per instr 1024 contiguous LDS bytes.
    // lane L: row = L>>3, LDS chunk = L&7, GLOBAL chunk = (L&7) ^ (L>>3).
    const int s_row   = lane >> 3;                    // 0..7
    const int s_chunk = lane & 7;
    const int s_col   = (s_chunk ^ s_row) * 8;        // bf16 elems (swizzled src)

    const unsigned short* Ag = A + (size_t)(bm + wid * 32 + s_row) * K + s_col;
    const unsigned short* Bg = B + (size_t)(bn + wid * 32 + s_row) * K + s_col;
    unsigned short* lAw = &lA[(wid * 32) * 64];
    unsigned short* lBw = &lB[(wid * 32) * 64];

    floatx4 acc[4][4];
#pragma unroll
    for (int i = 0; i < 4; i++)
#pragma unroll
        for (int j = 0; j < 4; j++)
            acc[i][j] = (floatx4){0.f, 0.f, 0.f, 0.f};

    const int fm = lane & 15;        // operand row (16-dim)
    const int q  = lane >> 4;        // quarter-wave -> k chunk
    const int sw = fm & 7;           // row swizzle factor

    for (int kt = 0; kt < K; kt += 64) {
#pragma unroll
        for (int i = 0; i < 4; i++) {
            async_copy16(Ag + (size_t)i * 8 * K + kt, lAw + i * 8 * 64);
            async_copy16(Bg + (size_t)i * 8 * K + kt, lBw + i * 8 * 64);
        }
        __syncthreads();

#pragma unroll
        for (int ks = 0; ks < 2; ks++) {
            // logical chunk = ks*4 + q; swizzled LDS chunk = that ^ (row&7)
            const int ko = ((ks * 4 + q) ^ sw) * 8;   // bf16 elem offset in row
            bf16x8 af[4], bfv[4];
#pragma unroll
            for (int i = 0; i < 4; i++) {
                af[i]  = *(const bf16x8*)&lA[(wm + i * 16 + fm) * 64 + ko];
                bfv[i] = *(const bf16x8*)&lB[(wn + i * 16 + fm) * 64 + ko];
            }
#pragma unroll
            for (int i = 0; i < 4; i++)
#pragma unroll
                for (int j = 0; j < 4; j++)
                    acc[i][j] = __builtin_amdgcn_mfma_f32_16x16x32_bf16(
                        af[i], bfv[j], acc[i][j], 0, 0, 0);
        }
        __syncthreads();
    }

    // epilogue: C/D layout col=lane&15, row=(lane>>4)*4+reg  (m89-verified)
    const int cn = lane & 15;
    const int cm = (lane >> 4) * 4;
#pragma unroll
    for (int j = 0; j < 4; j++) {
        const int col = bn + wn + j * 16 + cn;
        const float bv = bias[col];
#pragma unroll
        for (int i = 0; i < 4; i++) {
            const size_t rbase = (size_t)(bm + wm + i * 16 + cm) * N + col;
#pragma unroll
            for (int r = 0; r < 4; r++)
                C[rbase + (size_t)r * N] = acc[i][j][r] + bv;
        }
    }
}

extern "C" void kernel_launch(void* const* d_in, const int* in_sizes, int n_in,
                              void* d_out, int out_size, void* d_ws, size_t ws_size,
                              hipStream_t stream) {
    const float* x    = (const float*)d_in[0];   // [S,B,H] fp32
    const float* w    = (const float*)d_in[1];   // [O,H]  fp32
    const float* bias = (const float*)d_in[2];   // [O]    fp32
    float* out = (float*)d_out;

    const int O = in_sizes[2];
    const int H = in_sizes[1] / O;
    const long M = (long)in_sizes[0] / H;        // S*B = 16384

    unsigned short* xb = (unsigned short*)d_ws;            // [M*H] bf16
    unsigned short* wb = xb + (size_t)M * H;               // [O*H] bf16

    const long n8 = (long)M * H / 8;
    cvt_bf16_x8<<<dim3((n8 + 255) / 256), dim3(256), 0, stream>>>(
        (const float4*)x, (uint4*)xb, n8);

    const int ng = O * H / 4;
    sparsify_w<<<dim3((ng + 255) / 256), dim3(256), 0, stream>>>(
        (const float4*)w, (unsigned long long*)wb, ng);

    const int nblocks = (int)((M / 128) * (O / 128));      // 2048, 1D grid
    gemm_bt_bf16<<<dim3(nblocks), dim3(256), 0, stream>>>(xb, wb, bias, out,
                                                          (int)M, O, H);
}